// Round 23
// baseline (613.649 us; speedup 1.0000x reference)
//
#include <hip/hip_runtime.h>
#include <hip/hip_bf16.h>
#include <math.h>

#define BATCH 512
#define NI 627
#define NH 1024
#define NOUTF 1254
#define LLEN 627
#define NBL (512 * 627)
#define EPSBN 1e-5f
#define NSLOT 10240
#define NRED2 40
#define NRED34 20
#define NRED4 4

typedef __attribute__((ext_vector_type(8))) short bf16x8;
typedef __attribute__((ext_vector_type(4))) float f32x4;
typedef unsigned int uint32;
typedef unsigned short ushort16;

__device__ inline short f2b(float x) {
  __hip_bfloat16 h = __float2bfloat16(x);
  return *reinterpret_cast<short*>(&h);
}
__device__ inline float b2f(short s) {
  return __uint_as_float(((uint32)(ushort16)s) << 16);
}
__device__ inline f32x4 mfma16(bf16x8 a, bf16x8 b, f32x4 c) {
  return __builtin_amdgcn_mfma_f32_16x16x32_bf16(a, b, c, 0, 0, 0);
}
__device__ inline bf16x8 zero8() {
  bf16x8 z;
#pragma unroll
  for (int i = 0; i < 8; ++i) z[i] = 0;
  return z;
}
__device__ inline bf16x8 buildx1r(float4 alo, float4 ahi, float4 blo, float4 bhi, float th) {
  bf16x8 r;
  r[0] = f2b(fmaxf(fmaf(alo.x, th, blo.x), 0.f));
  r[1] = f2b(fmaxf(fmaf(alo.y, th, blo.y), 0.f));
  r[2] = f2b(fmaxf(fmaf(alo.z, th, blo.z), 0.f));
  r[3] = f2b(fmaxf(fmaf(alo.w, th, blo.w), 0.f));
  r[4] = f2b(fmaxf(fmaf(ahi.x, th, bhi.x), 0.f));
  r[5] = f2b(fmaxf(fmaf(ahi.y, th, bhi.y), 0.f));
  r[6] = f2b(fmaxf(fmaf(ahi.z, th, bhi.z), 0.f));
  r[7] = f2b(fmaxf(fmaf(ahi.w, th, bhi.w), 0.f));
  return r;
}
__device__ inline bf16x8 buildx1(const float* __restrict__ A1v, const float* __restrict__ B1v,
                                 int k0, float th) {
  float4 alo = *reinterpret_cast<const float4*>(&A1v[k0]);
  float4 ahi = *reinterpret_cast<const float4*>(&A1v[k0 + 4]);
  float4 blo = *reinterpret_cast<const float4*>(&B1v[k0]);
  float4 bhi = *reinterpret_cast<const float4*>(&B1v[k0 + 4]);
  return buildx1r(alo, ahi, blo, bhi, th);
}

// ================= fused prep =================
__device__ inline void prep_mlpw_elem(const float* W, short* Wb, int i,
                                      int Nreal, int Kreal, int Kpad, int mode) {
  int n = i / Kpad, k = i - n * Kpad;
  float w = 0.f;
  if (n < Nreal && k < Kreal) {
    int od = n >= 627 ? n - 627 : n;
    int kd = k >= 627 ? k - 627 : k;
    bool keep = (mode == 0) ? (od >= k) : (mode == 1) ? (od >= kd) : (od > kd);
    if (keep) w = W[n * Kreal + k];
  }
  Wb[i] = f2b(w);
}
__device__ inline void prep_convw_elem(const float* W, short* Wb, int i,
                                       int Oreal, int Kreal, int Kpad) {
  int o = i / Kpad, k = i - o * Kpad;
  Wb[i] = (o < Oreal && k < Kreal) ? f2b(W[o * Kreal + k]) : (short)0;
}

#define PB_INB   1280
#define PB_WB1   (PB_INB + 2560)
#define PB_WB2   (PB_WB1 + 4096)
#define PB_WB3   (PB_WB2 + 4096)
#define PB_WB4   (PB_WB3 + 5120)
#define PB_CW2   (PB_WB4 + 72)
#define PB_CW3   (PB_CW2 + 144)
#define PB_CW4   (PB_CW3 + 144)
#define PB_CW5   (PB_CW4 + 240)
#define PB_CB    (PB_CW5 + 2)

__global__ __launch_bounds__(256) void prep_all(
    const float* __restrict__ inputs, short* __restrict__ INB,
    const float* __restrict__ W_in, short* __restrict__ WB1,
    const float* __restrict__ W_h1, short* __restrict__ WB2,
    const float* __restrict__ W_h2, short* __restrict__ WB3,
    const float* __restrict__ W_out, short* __restrict__ WB4,
    const float* __restrict__ cw2, short* __restrict__ CW2B,
    const float* __restrict__ cw3, short* __restrict__ CW3B,
    const float* __restrict__ cw4, short* __restrict__ CW4B,
    const float* __restrict__ cw5, short* __restrict__ CW5B,
    const float* __restrict__ cb2, const float* __restrict__ cb3,
    const float* __restrict__ cb4, const float* __restrict__ cb5,
    float* __restrict__ cb2p, float* __restrict__ cb3p,
    float* __restrict__ cb4p, float* __restrict__ cb5p)
{
  const int bid = blockIdx.x;
  if (bid < PB_INB) {
    int i = bid * 256 + threadIdx.x;
    if (i < 512 * 640) {
      int m = i / 640, k = i - m * 640;
      INB[i] = (k < NI) ? f2b(inputs[m * NI + k]) : (short)0;
    }
  } else if (bid < PB_WB1) {
    int i = (bid - PB_INB) * 256 + threadIdx.x;
    if (i < 1024 * 640) prep_mlpw_elem(W_in, WB1, i, 1024, 627, 640, 0);
  } else if (bid < PB_WB2) {
    int i = (bid - PB_WB1) * 256 + threadIdx.x;
    prep_mlpw_elem(W_h1, WB2, i, 1024, 1024, 1024, 1);
  } else if (bid < PB_WB3) {
    int i = (bid - PB_WB2) * 256 + threadIdx.x;
    prep_mlpw_elem(W_h2, WB3, i, 1024, 1024, 1024, 1);
  } else if (bid < PB_WB4) {
    int i = (bid - PB_WB3) * 256 + threadIdx.x;
    if (i < 1280 * 1024) prep_mlpw_elem(W_out, WB4, i, 1254, 1024, 1024, 2);
  } else if (bid < PB_CW2) {
    int i = (bid - PB_WB4) * 256 + threadIdx.x;
    if (i < 192 * 96) prep_convw_elem(cw2, CW2B, i, 180, 90, 96);
  } else if (bid < PB_CW3) {
    int i = (bid - PB_CW2) * 256 + threadIdx.x;
    if (i < 192 * 192) prep_convw_elem(cw3, CW3B, i, 180, 180, 192);
  } else if (bid < PB_CW4) {
    int i = (bid - PB_CW3) * 256 + threadIdx.x;
    if (i < 192 * 192) prep_convw_elem(cw4, CW4B, i, 180, 180, 192);
  } else if (bid < PB_CW5) {
    int i = (bid - PB_CW4) * 256 + threadIdx.x;
    if (i < 320 * 192) prep_convw_elem(cw5, CW5B, i, 300, 180, 192);
  } else {
    int c = (bid - PB_CW5) * 256 + threadIdx.x;
    if (c < 192) {
      cb2p[c] = (c < 180) ? cb2[c] : 0.f;
      cb3p[c] = (c < 180) ? cb3[c] : 0.f;
      cb4p[c] = (c < 180) ? cb4[c] : 0.f;
    }
    if (c < 320) cb5p[c] = (c < 300) ? cb5[c] : 0.f;
  }
}

// ====== MLP MFMA GEMM ======
template<int KPAD>
__global__ __launch_bounds__(256) void mlp_mfma(
    const short* __restrict__ A, const short* __restrict__ Wb, const float* __restrict__ bias,
    float* __restrict__ Cf, short* __restrict__ Cb, int Nreal, int relu)
{
  __shared__ float red[2][2][2][4][64];
  const int tid = threadIdx.x;
  const int l = tid & 63, wv = tid >> 6;
  const int wn = wv >> 1, kh = wv & 1;
  const int m0 = blockIdx.y * 32;
  const int n0 = blockIdx.x * 64 + wn * 32;
  const int lr = l & 15, lk = (l >> 4) * 8, lm4 = (l >> 4) * 4;
  f32x4 acc[2][2] = {};
  constexpr int khalf = KPAD >> 1;
  constexpr int nk = khalf >> 5;
#pragma unroll
  for (int ks = 0; ks < nk; ++ks) {
    int k0 = kh * khalf + ks * 32 + lk;
    bf16x8 a0 = *reinterpret_cast<const bf16x8*>(&A[(size_t)(m0 + lr) * KPAD + k0]);
    bf16x8 a1 = *reinterpret_cast<const bf16x8*>(&A[(size_t)(m0 + 16 + lr) * KPAD + k0]);
    bf16x8 b0 = *reinterpret_cast<const bf16x8*>(&Wb[(size_t)(n0 + lr) * KPAD + k0]);
    bf16x8 b1 = *reinterpret_cast<const bf16x8*>(&Wb[(size_t)(n0 + 16 + lr) * KPAD + k0]);
    acc[0][0] = mfma16(a0, b0, acc[0][0]);
    acc[0][1] = mfma16(a0, b1, acc[0][1]);
    acc[1][0] = mfma16(a1, b0, acc[1][0]);
    acc[1][1] = mfma16(a1, b1, acc[1][1]);
  }
  if (kh == 1) {
#pragma unroll
    for (int mi = 0; mi < 2; ++mi)
#pragma unroll
      for (int nj = 0; nj < 2; ++nj)
#pragma unroll
        for (int r = 0; r < 4; ++r) red[wn][mi][nj][r][l] = acc[mi][nj][r];
  }
  __syncthreads();
  if (kh == 0) {
#pragma unroll
    for (int mi = 0; mi < 2; ++mi)
#pragma unroll
      for (int nj = 0; nj < 2; ++nj) {
        int n = n0 + nj * 16 + lr;
        if (n >= Nreal) continue;
        float bi = bias[n];
#pragma unroll
        for (int r = 0; r < 4; ++r) {
          int m = m0 + mi * 16 + lm4 + r;
          float v = acc[mi][nj][r] + red[wn][mi][nj][r][l] + bi;
          if (relu) v = fmaxf(v, 0.f);
          if (Cb) Cb[(size_t)m * Nreal + n] = f2b(v);
          else Cf[(size_t)m * Nreal + n] = v;
        }
      }
  }
}

// ================= theta stats =================
__global__ __launch_bounds__(256) void theta_stats(const float* __restrict__ outb, float* __restrict__ tstat)
{
  int b = blockIdx.x;
  const float* th = outb + (size_t)b * NOUTF + NI;
  float s = 0.f, q = 0.f;
  for (int l = threadIdx.x; l < LLEN; l += 256) { float t = th[l]; s += t; q += t * t; }
  for (int off = 1; off < 64; off <<= 1) { s += __shfl_xor(s, off); q += __shfl_xor(q, off); }
  __shared__ float tmp[8];
  int w = threadIdx.x >> 6;
  if ((threadIdx.x & 63) == 0) { tmp[w] = s; tmp[4 + w] = q; }
  __syncthreads();
  if (threadIdx.x == 0) {
    atomicAdd(&tstat[0], tmp[0] + tmp[1] + tmp[2] + tmp[3]);
    atomicAdd(&tstat[1], tmp[4] + tmp[5] + tmp[6] + tmp[7]);
  }
}

__global__ void finalize_conv1(const float* __restrict__ tstat, const float* __restrict__ cw1,
                               const float* __restrict__ g1, const float* __restrict__ be1,
                               float* __restrict__ a1, float* __restrict__ b1)
{
  int c = threadIdx.x;  // 96
  if (c >= 96) return;
  if (c < 90) {
    float mt = tstat[0] / (float)NBL;
    float vt = tstat[1] / (float)NBL - mt * mt;
    float w = cw1[c];
    float rs = rsqrtf(w * w * vt + EPSBN);
    float a = w * g1[c] * rs;
    a1[c] = a;
    b1[c] = be1[c] - a * mt;
  } else { a1[c] = 0.f; b1[c] = 0.f; }
}

// ============ BN stats reduction ============
__global__ __launch_bounds__(192) void bn_reduce1(const float* __restrict__ Sp, const float* __restrict__ Qp,
                                                  float* __restrict__ Sred, float* __restrict__ Qred)
{
  int c = threadIdx.x;
  if (c >= 180) return;
  int base = blockIdx.x * 256;
  float s = 0.f, q = 0.f;
  for (int r = 0; r < 256; ++r) {
    s += Sp[(size_t)(base + r) * 180 + c];
    q += Qp[(size_t)(base + r) * 180 + c];
  }
  Sred[blockIdx.x * 180 + c] = s;
  Qred[blockIdx.x * 180 + c] = q;
}

__global__ void finalize_bn2(const float* __restrict__ Sred, const float* __restrict__ Qred,
                             const float* __restrict__ g, const float* __restrict__ be,
                             float* __restrict__ aP, float* __restrict__ bP, int nred)
{
  int c = threadIdx.x;  // 192
  if (c >= 192) return;
  if (c < 180) {
    float s = 0.f, q = 0.f;
    for (int p = 0; p < nred; ++p) { s += Sred[p * 180 + c]; q += Qred[p * 180 + c]; }
    float m = s / (float)NBL;
    float v = q / (float)NBL - m * m;
    float a = g[c] * rsqrtf(v + EPSBN);
    aP[c] = a;
    bP[c] = be[c] - m * a;
  } else { aP[c] = 0.f; bP[c] = 0.f; }
}

// ================= conv2 stats-only =================
__global__ __launch_bounds__(512) void conv2_stats(
    const float* __restrict__ OUTB, const float* __restrict__ A1v, const float* __restrict__ B1v,
    const short* __restrict__ cw2b, const float* __restrict__ cb2p,
    float* __restrict__ Sp, float* __restrict__ Qp)
{
  const int tid = threadIdx.x;
  const int b = blockIdx.y, j0 = blockIdx.x * 128;
  const int l = tid & 63, wv = tid >> 6, wm = wv >> 2, wn = wv & 3;
  const int lr = l & 15, lk = (l >> 4) * 8, lm4 = (l >> 4) * 4;
  const int jj0 = j0 + wn * 32 + lr, jj1 = jj0 + 16;
  const float th0 = (jj0 < LLEN) ? OUTB[(size_t)b * NOUTF + NI + jj0] : 0.f;
  const float th1 = (jj1 < LLEN) ? OUTB[(size_t)b * NOUTF + NI + jj1] : 0.f;
  f32x4 acc[6][2] = {};
#pragma unroll
  for (int ks = 0; ks < 3; ++ks) {
    int k0 = ks * 32 + lk;
    bf16x8 b0 = buildx1(A1v, B1v, k0, th0);
    bf16x8 b1 = buildx1(A1v, B1v, k0, th1);
#pragma unroll
    for (int mi = 0; mi < 6; ++mi) {
      bf16x8 av = *reinterpret_cast<const bf16x8*>(&cw2b[(wm * 96 + mi * 16 + lr) * 96 + k0]);
      acc[mi][0] = mfma16(av, b0, acc[mi][0]);
      acc[mi][1] = mfma16(av, b1, acc[mi][1]);
    }
  }
  const size_t slot = (size_t)(blockIdx.y * gridDim.x + blockIdx.x) * 4 + wn;
#pragma unroll
  for (int mi = 0; mi < 6; ++mi) {
    int m0c = wm * 96 + mi * 16 + lm4;
    float s4[4] = {0.f, 0.f, 0.f, 0.f}, q4[4] = {0.f, 0.f, 0.f, 0.f};
#pragma unroll
    for (int nj = 0; nj < 2; ++nj) {
      int jj = j0 + wn * 32 + nj * 16 + lr;
      if (jj < LLEN) {
#pragma unroll
        for (int r = 0; r < 4; ++r) {
          float v = acc[mi][nj][r] + cb2p[m0c + r];
          s4[r] += v; q4[r] += v * v;
        }
      }
    }
#pragma unroll
    for (int off = 1; off < 16; off <<= 1)
#pragma unroll
      for (int r = 0; r < 4; ++r) { s4[r] += __shfl_xor(s4[r], off); q4[r] += __shfl_xor(q4[r], off); }
    if (lr == 0) {
#pragma unroll
      for (int r = 0; r < 4; ++r) {
        int o = m0c + r;
        if (o < 180) {
          Sp[slot * 180 + o] = s4[r];
          Qp[slot * 180 + o] = q4[r];
        }
      }
    }
  }
}

// ==== fused conv2->bn2->relu->conv3: PERSISTENT, weights from L2 (LDS = xT2 only, 50 KB) ====
__global__ __launch_bounds__(512) void fused_conv23(
    const float* __restrict__ OUTB, const float* __restrict__ A1v, const float* __restrict__ B1v,
    const short* __restrict__ cw2b, const float* __restrict__ cb2p,
    const float* __restrict__ a2, const float* __restrict__ b2,
    const short* __restrict__ cw3b, const float* __restrict__ cb3p,
    short* __restrict__ Y, float* __restrict__ Sp, float* __restrict__ Qp)
{
  __shared__ short xT2[128][196];  // 50.2 KB -> 3 blocks/CU by LDS
  const int tid = threadIdx.x;
  const int b = blockIdx.x;
  const int l = tid & 63, wv = tid >> 6, wm = wv >> 1, wn = wv & 1;
  const int lr = l & 15, lk = (l >> 4) * 8, lm4 = (l >> 4) * 4;
  float a2r[3][4], f2r[3][4], cb3r[3][4];
#pragma unroll
  for (int mi = 0; mi < 3; ++mi)
#pragma unroll
    for (int r = 0; r < 4; ++r) {
      int c = wm * 48 + mi * 16 + lm4 + r;
      float a = a2[c];
      a2r[mi][r] = a;
      f2r[mi][r] = fmaf(a, cb2p[c], b2[c]);
      cb3r[mi][r] = cb3p[c];
    }
  for (int tile = 0; tile < 5; ++tile) {
    const int j0 = tile * 128;
    float th[4];
#pragma unroll
    for (int nj = 0; nj < 4; ++nj) {
      int jj = j0 + wn * 64 + nj * 16 + lr;
      th[nj] = (jj < LLEN) ? OUTB[(size_t)b * NOUTF + NI + jj] : 0.f;
    }
    f32x4 acc[3][4] = {};
#pragma unroll
    for (int ks = 0; ks < 3; ++ks) {
      int k0 = ks * 32 + lk;
      float4 alo = *reinterpret_cast<const float4*>(&A1v[k0]);
      float4 ahi = *reinterpret_cast<const float4*>(&A1v[k0 + 4]);
      float4 blo = *reinterpret_cast<const float4*>(&B1v[k0]);
      float4 bhi = *reinterpret_cast<const float4*>(&B1v[k0 + 4]);
      bf16x8 bb[4];
#pragma unroll
      for (int nj = 0; nj < 4; ++nj) bb[nj] = buildx1r(alo, ahi, blo, bhi, th[nj]);
      bf16x8 av[3];
#pragma unroll
      for (int mi = 0; mi < 3; ++mi)
        av[mi] = *reinterpret_cast<const bf16x8*>(&cw2b[(wm * 48 + mi * 16 + lr) * 96 + k0]);
#pragma unroll
      for (int mi = 0; mi < 3; ++mi)
#pragma unroll
        for (int nj = 0; nj < 4; ++nj)
          acc[mi][nj] = mfma16(av[mi], bb[nj], acc[mi][nj]);
    }
    __syncthreads();  // prev tile's copy-out LDS reads done
#pragma unroll
    for (int mi = 0; mi < 3; ++mi) {
      int m0c = wm * 48 + mi * 16 + lm4;
#pragma unroll
      for (int nj = 0; nj < 4; ++nj) {
        int col = wn * 64 + nj * 16 + lr;
        float x0 = fmaxf(fmaf(a2r[mi][0], acc[mi][nj][0], f2r[mi][0]), 0.f);
        float x1 = fmaxf(fmaf(a2r[mi][1], acc[mi][nj][1], f2r[mi][1]), 0.f);
        float x2 = fmaxf(fmaf(a2r[mi][2], acc[mi][nj][2], f2r[mi][2]), 0.f);
        float x3 = fmaxf(fmaf(a2r[mi][3], acc[mi][nj][3], f2r[mi][3]), 0.f);
        uint2 w2;
        w2.x = (uint32)(ushort16)f2b(x0) | ((uint32)(ushort16)f2b(x1) << 16);
        w2.y = (uint32)(ushort16)f2b(x2) | ((uint32)(ushort16)f2b(x3) << 16);
        *reinterpret_cast<uint2*>(&xT2[col][m0c]) = w2;
      }
    }
    __syncthreads();
    f32x4 acc2[3][4] = {};
#pragma unroll
    for (int ks = 0; ks < 6; ++ks) {
      int k0 = ks * 32 + lk;
      bf16x8 bb[4];
#pragma unroll
      for (int nj = 0; nj < 4; ++nj)
        bb[nj] = *reinterpret_cast<const bf16x8*>(&xT2[wn * 64 + nj * 16 + lr][k0]);
      bf16x8 av[3];
#pragma unroll
      for (int mi = 0; mi < 3; ++mi)
        av[mi] = *reinterpret_cast<const bf16x8*>(&cw3b[(wm * 48 + mi * 16 + lr) * 192 + k0]);
#pragma unroll
      for (int mi = 0; mi < 3; ++mi)
#pragma unroll
        for (int nj = 0; nj < 4; ++nj)
          acc2[mi][nj] = mfma16(av[mi], bb[nj], acc2[mi][nj]);
    }
    __syncthreads();
    const size_t slot = ((size_t)b * 5 + tile) * 2 + wn;
#pragma unroll
    for (int mi = 0; mi < 3; ++mi) {
      int m0c = wm * 48 + mi * 16 + lm4;
      float s4[4] = {0.f, 0.f, 0.f, 0.f}, q4[4] = {0.f, 0.f, 0.f, 0.f};
#pragma unroll
      for (int nj = 0; nj < 4; ++nj) {
        int col = wn * 64 + nj * 16 + lr;
        int jj = j0 + col;
        float v0 = acc2[mi][nj][0] + cb3r[mi][0];
        float v1 = acc2[mi][nj][1] + cb3r[mi][1];
        float v2 = acc2[mi][nj][2] + cb3r[mi][2];
        float v3 = acc2[mi][nj][3] + cb3r[mi][3];
        if (jj < LLEN) {
          s4[0] += v0; q4[0] += v0 * v0;
          s4[1] += v1; q4[1] += v1 * v1;
          s4[2] += v2; q4[2] += v2 * v2;
          s4[3] += v3; q4[3] += v3 * v3;
        }
        uint2 w2;
        w2.x = (uint32)(ushort16)f2b(v0) | ((uint32)(ushort16)f2b(v1) << 16);
        w2.y = (uint32)(ushort16)f2b(v2) | ((uint32)(ushort16)f2b(v3) << 16);
        *reinterpret_cast<uint2*>(&xT2[col][m0c]) = w2;
      }
#pragma unroll
      for (int off = 1; off < 16; off <<= 1)
#pragma unroll
        for (int r = 0; r < 4; ++r) { s4[r] += __shfl_xor(s4[r], off); q4[r] += __shfl_xor(q4[r], off); }
      if (lr == 0) {
#pragma unroll
        for (int r = 0; r < 4; ++r) {
          int o = m0c + r;
          if (o < 180) {
            Sp[slot * 180 + o] = s4[r];
            Qp[slot * 180 + o] = q4[r];
          }
        }
      }
    }
    __syncthreads();
    for (int f = tid; f < 128 * 24; f += 512) {
      int row = f / 24, c0 = (f - row * 24) * 8;
      int jj = j0 + row;
      if (jj < LLEN) {
        bf16x8 v = *reinterpret_cast<const bf16x8*>(&xT2[row][c0]);
        *reinterpret_cast<bf16x8*>(&Y[((size_t)b * 627 + jj) * 192 + c0]) = v;
      }
    }
  }
}

// ====== conv4 in place on Y: PERSISTENT + register Y-prefetch (T14) + reg stats ======
__global__ __launch_bounds__(512) void conv4_ip(
    short* __restrict__ Y, const float* __restrict__ a3, const float* __restrict__ b3,
    const short* __restrict__ cw4b, const float* __restrict__ cb4p,
    float* __restrict__ Sp, float* __restrict__ Qp)
{
  __shared__ short wl4[192][196];  // 75.3 KB
  __shared__ short xT[128][196];   // 50.2 KB
  __shared__ float ab[384];        // 1.5 KB
  const int tid = threadIdx.x;
  const int b = blockIdx.x;
  for (int t = tid; t < 192 * 24; t += 512) {
    int row = t / 24, c8 = (t - row * 24) * 8;
    *reinterpret_cast<bf16x8*>(&wl4[row][c8]) = *reinterpret_cast<const bf16x8*>(&cw4b[row * 192 + c8]);
  }
  for (int t = tid; t < 384; t += 512) ab[t] = (t < 192) ? a3[t] : b3[t - 192];
  const int l = tid & 63, wv = tid >> 6, wm = wv >> 1, wn = wv & 1;
  const int lr = l & 15, lk = (l >> 4) * 8, lm4 = (l >> 4) * 4;
  float cb4r[3][4];
#pragma unroll
  for (int mi = 0; mi < 3; ++mi)
#pragma unroll
    for (int r = 0; r < 4; ++r)
      cb4r[mi][r] = cb4p[wm * 48 + mi * 16 + lm4 + r];
  // prefetch tile 0 raw Y (6 chunks/thread)
  bf16x8 raw[6];
#pragma unroll
  for (int s = 0; s < 6; ++s) {
    int t = tid + s * 512;
    int col = t / 24, c8 = (t - col * 24) * 8;
    raw[s] = (col < LLEN) ? *reinterpret_cast<const bf16x8*>(&Y[((size_t)b * 627 + col) * 192 + c8]) : zero8();
  }
  float sacc[3][4] = {}, qacc[3][4] = {};
  __syncthreads();  // wl4/ab visible
  for (int tile = 0; tile < 5; ++tile) {
    const int j0 = tile * 128;
    // convert prefetched raw -> xT (x3 = relu(a3*y3+b3))
#pragma unroll
    for (int s = 0; s < 6; ++s) {
      int t = tid + s * 512;
      int col = t / 24, c8 = (t - col * 24) * 8;
      int jj = j0 + col;
      bf16x8 pk;
      if (jj < LLEN) {
#pragma unroll
        for (int i = 0; i < 8; ++i)
          pk[i] = f2b(fmaxf(fmaf(ab[c8 + i], b2f(raw[s][i]), ab[192 + c8 + i]), 0.f));
      } else {
        pk = zero8();
      }
      *reinterpret_cast<bf16x8*>(&xT[col][c8]) = pk;
    }
    __syncthreads();  // xT ready
    f32x4 acc[3][4] = {};
#pragma unroll
    for (int ks = 0; ks < 6; ++ks) {
      int k0 = ks * 32 + lk;
      bf16x8 bb[4];
#pragma unroll
      for (int nj = 0; nj < 4; ++nj)
        bb[nj] = *reinterpret_cast<const bf16x8*>(&xT[wn * 64 + nj * 16 + lr][k0]);
      bf16x8 av[3];
#pragma unroll
      for (int mi = 0; mi < 3; ++mi)
        av[mi] = *reinterpret_cast<const bf16x8*>(&wl4[wm * 48 + mi * 16 + lr][k0]);
#pragma unroll
      for (int mi = 0; mi < 3; ++mi)
#pragma unroll
        for (int nj = 0; nj < 4; ++nj)
          acc[mi][nj] = mfma16(av[mi], bb[nj], acc[mi][nj]);
    }
    // issue next tile's Y loads (latency hidden under epilogue + copy-out)
    if (tile < 4) {
#pragma unroll
      for (int s = 0; s < 6; ++s) {
        int t = tid + s * 512;
        int col = t / 24, c8 = (t - col * 24) * 8;
        int jj = j0 + 128 + col;
        raw[s] = (jj < LLEN) ? *reinterpret_cast<const bf16x8*>(&Y[((size_t)b * 627 + jj) * 192 + c8]) : zero8();
      }
    }
    __syncthreads();  // MFMA xT reads done; reuse xT as y4 staging
#pragma unroll
    for (int mi = 0; mi < 3; ++mi) {
      int m0c = wm * 48 + mi * 16 + lm4;
#pragma unroll
      for (int nj = 0; nj < 4; ++nj) {
        int col = wn * 64 + nj * 16 + lr;
        int jj = j0 + col;
        float v0 = acc[mi][nj][0] + cb4r[mi][0];
        float v1 = acc[mi][nj][1] + cb4r[mi][1];
        float v2 = acc[mi][nj][2] + cb4r[mi][2];
        float v3 = acc[mi][nj][3] + cb4r[mi][3];
        if (jj < LLEN) {
          sacc[mi][0] += v0; qacc[mi][0] += v0 * v0;
          sacc[mi][1] += v1; qacc[mi][1] += v1 * v1;
          sacc[mi][2] += v2; qacc[mi][2] += v2 * v2;
          sacc[mi][3] += v3; qacc[mi][3] += v3 * v3;
        }
        uint2 w2;
        w2.x = (uint32)(ushort16)f2b(v0) | ((uint32)(ushort16)f2b(v1) << 16);
        w2.y = (uint32)(ushort16)f2b(v2) | ((uint32)(ushort16)f2b(v3) << 16);
        *reinterpret_cast<uint2*>(&xT[col][m0c]) = w2;
      }
    }
    __syncthreads();  // y4 staged
    for (int f = tid; f < 128 * 24; f += 512) {
      int row = f / 24, c0 = (f - row * 24) * 8;
      int jj = j0 + row;
      if (jj < LLEN) {
        bf16x8 v = *reinterpret_cast<const bf16x8*>(&xT[row][c0]);
        *reinterpret_cast<bf16x8*>(&Y[((size_t)b * 627 + jj) * 192 + c0]) = v;
      }
    }
    __syncthreads();  // copy-out reads done before next convert overwrites xT
  }
  // final stats write (once per block)
  const size_t slot = (size_t)b * 2 + wn;
#pragma unroll
  for (int mi = 0; mi < 3; ++mi) {
#pragma unroll
    for (int off = 1; off < 16; off <<= 1)
#pragma unroll
      for (int r = 0; r < 4; ++r) {
        sacc[mi][r] += __shfl_xor(sacc[mi][r], off);
        qacc[mi][r] += __shfl_xor(qacc[mi][r], off);
      }
    if (lr == 0) {
      int m0c = wm * 48 + mi * 16 + lm4;
#pragma unroll
      for (int r = 0; r < 4; ++r) {
        int o = m0c + r;
        if (o < 180) {
          Sp[slot * 180 + o] = sacc[mi][r];
          Qp[slot * 180 + o] = qacc[mi][r];
        }
      }
    }
  }
}

// ==== conv5 + softmax + NLL + ll reduction: weights from L2 (LDS ~33 KB) ====
__global__ __launch_bounds__(512) void conv5_nll_ll(
    const short* __restrict__ Y, const float* __restrict__ a4, const float* __restrict__ b4,
    const short* __restrict__ cw5b, const float* __restrict__ cb5p,
    const float* __restrict__ inputs, const float* __restrict__ outb,
    float* __restrict__ llp, float* __restrict__ sc)
{
  __shared__ short xT[64][200];
  __shared__ int tga[640];
  __shared__ float wmax[4][64];
  __shared__ float wsum[4][64];
  __shared__ float ptgt[64];
  __shared__ float nlls[640];
  const int tid = threadIdx.x;
  const int b = blockIdx.x;
  for (int t = tid; t < 640; t += 512)
    tga[t] = (t < LLEN) ? (int)inputs[(size_t)b * NI + t] : 0;
  const int l = tid & 63, wv = tid >> 6;
  const int wm = wv >> 1, wn = wv & 1;
  const int lr = l & 15, lk = (l >> 4) * 8, lm4 = (l >> 4) * 4;
  const int mf0 = wm * 5;
  float aa[3][8], bb4[3][8];
#pragma unroll
  for (int s = 0; s < 3; ++s) {
    int t = tid + s * 512;
    int c8 = (t % 24) * 8;
#pragma unroll
    for (int i = 0; i < 8; ++i) { aa[s][i] = a4[c8 + i]; bb4[s][i] = b4[c8 + i]; }
  }
  float cbr[5][4];
#pragma unroll
  for (int mi = 0; mi < 5; ++mi)
#pragma unroll
    for (int r = 0; r < 4; ++r)
      cbr[mi][r] = cb5p[(mf0 + mi) * 16 + lm4 + r];
  bf16x8 raw[3];
#pragma unroll
  for (int s = 0; s < 3; ++s) {
    int t = tid + s * 512;
    int col = t / 24, c8 = (t - col * 24) * 8;
    raw[s] = (col < LLEN) ? *reinterpret_cast<const bf16x8*>(&Y[((size_t)b * 627 + col) * 192 + c8]) : zero8();
  }
  __syncthreads();
  for (int tile = 0; tile < 10; ++tile) {
    const int l0 = tile * 64;
#pragma unroll
    for (int s = 0; s < 3; ++s) {
      int t = tid + s * 512;
      int col = t / 24, c8 = (t - col * 24) * 8;
      bf16x8 pk;
#pragma unroll
      for (int i = 0; i < 8; ++i)
        pk[i] = f2b(fmaxf(fmaf(aa[s][i], b2f(raw[s][i]), bb4[s][i]), 0.f));
      *reinterpret_cast<bf16x8*>(&xT[col][c8]) = pk;
    }
    __syncthreads();
    f32x4 acc[5][2] = {};
#pragma unroll
    for (int ks = 0; ks < 6; ++ks) {
      int k0 = ks * 32 + lk;
      bf16x8 bb0 = *reinterpret_cast<const bf16x8*>(&xT[wn * 32 + lr][k0]);
      bf16x8 bb1 = *reinterpret_cast<const bf16x8*>(&xT[wn * 32 + 16 + lr][k0]);
#pragma unroll
      for (int mi = 0; mi < 5; ++mi) {
        bf16x8 av = *reinterpret_cast<const bf16x8*>(&cw5b[((mf0 + mi) * 16 + lr) * 192 + k0]);
        acc[mi][0] = mfma16(av, bb0, acc[mi][0]);
        acc[mi][1] = mfma16(av, bb1, acc[mi][1]);
      }
    }
    if (tile < 9) {
#pragma unroll
      for (int s = 0; s < 3; ++s) {
        int t = tid + s * 512;
        int col = t / 24, c8 = (t - col * 24) * 8;
        int jj = l0 + 64 + col;
        raw[s] = (jj < LLEN) ? *reinterpret_cast<const bf16x8*>(&Y[((size_t)b * 627 + jj) * 192 + c8]) : zero8();
      }
    }
    float vmax0 = -1e30f, vmax1 = -1e30f;
    int t0 = tga[l0 + wn * 32 + lr], t1 = tga[l0 + wn * 32 + 16 + lr];
#pragma unroll
    for (int mi = 0; mi < 5; ++mi) {
#pragma unroll
      for (int r = 0; r < 4; ++r) {
        int m = (mf0 + mi) * 16 + lm4 + r;
        bool ok = (m < 300);
        float v0 = ok ? (acc[mi][0][r] + cbr[mi][r]) : -1e30f;
        float v1 = ok ? (acc[mi][1][r] + cbr[mi][r]) : -1e30f;
        acc[mi][0][r] = v0;
        acc[mi][1][r] = v1;
        vmax0 = fmaxf(vmax0, v0);
        vmax1 = fmaxf(vmax1, v1);
        if (m == t0) ptgt[wn * 32 + lr] = v0;
        if (m == t1) ptgt[wn * 32 + 16 + lr] = v1;
      }
    }
    vmax0 = fmaxf(vmax0, __shfl_xor(vmax0, 16)); vmax0 = fmaxf(vmax0, __shfl_xor(vmax0, 32));
    vmax1 = fmaxf(vmax1, __shfl_xor(vmax1, 16)); vmax1 = fmaxf(vmax1, __shfl_xor(vmax1, 32));
    float vs0 = 0.f, vs1 = 0.f;
#pragma unroll
    for (int mi = 0; mi < 5; ++mi)
#pragma unroll
      for (int r = 0; r < 4; ++r) {
        vs0 += __expf(acc[mi][0][r] - vmax0);
        vs1 += __expf(acc[mi][1][r] - vmax1);
      }
    vs0 += __shfl_xor(vs0, 16); vs0 += __shfl_xor(vs0, 32);
    vs1 += __shfl_xor(vs1, 16); vs1 += __shfl_xor(vs1, 32);
    if (l < 16) {
      wmax[wm][wn * 32 + lr] = vmax0; wmax[wm][wn * 32 + 16 + lr] = vmax1;
      wsum[wm][wn * 32 + lr] = vs0;   wsum[wm][wn * 32 + 16 + lr] = vs1;
    }
    __syncthreads();
    if (tid < 64) {
      int jj = l0 + tid;
      if (jj < LLEN) {
        float m0 = wmax[0][tid], m1 = wmax[1][tid], m2 = wmax[2][tid], m3 = wmax[3][tid];
        float gm = fmaxf(fmaxf(m0, m1), fmaxf(m2, m3));
        float gs = wsum[0][tid] * __expf(m0 - gm) + wsum[1][tid] * __expf(m1 - gm)
                 + wsum[2][tid] * __expf(m2 - gm) + wsum[3][tid] * __expf(m3 - gm);
        nlls[jj] = gm + logf(gs) - ptgt[tid];
      }
    }
  }
  __syncthreads();
  float s = 0.f;
  for (int lidx = 2 + tid; lidx < LLEN; lidx += 512) {
    float graw = outb[(size_t)b * NOUTF + lidx];
    float sg = 1.f / (1.f + expf(-graw));
    float term = (tga[lidx] > 0) ? (0.1f * logf(sg + 1e-10f) - nlls[lidx])
                                 : (0.1f * logf(1.f - sg + 1e-10f));
    s += term;
  }
  for (int off = 1; off < 64; off <<= 1) s += __shfl_xor(s, off);
  if (l == 0) wmax[0][wv] = s;
  __syncthreads();
  if (tid == 0) {
    float tot = 0.f;
#pragma unroll
    for (int w = 0; w < 8; ++w) tot += wmax[0][w];
    llp[b] = tot;
    atomicAdd(sc, nlls[0] + nlls[1]);
  }
}

__global__ void ll_pass2(const float* __restrict__ llp, const float* __restrict__ sc, float* __restrict__ outp)
{
  int i = blockIdx.x * blockDim.x + threadIdx.x;
  if (i < BATCH) outp[i] = llp[i] - sc[0] * (1.f / 1024.f);
}

extern "C" void kernel_launch(void* const* d_in, const int* in_sizes, int n_in,
                              void* d_out, int out_size, void* d_ws, size_t ws_size,
                              hipStream_t stream)
{
  const float* inputs = (const float*)d_in[0];
  const float* W_in = (const float*)d_in[1];
  const float* b_in = (const float*)d_in[2];
  const float* W_h1 = (const float*)d_in[3];
  const float* b_h1 = (const float*)d_in[4];
  const float* W_h2 = (const float*)d_in[5];
  const float* b_h2 = (const float*)d_in[6];
  const float* W_out = (const float*)d_in[7];
  const float* b_out = (const float*)d_in[8];
  const float* cw1 = (const float*)d_in[9];
  const float* g1 = (const float*)d_in[11];
  const float* be1 = (const float*)d_in[12];
  const float* cw2 = (const float*)d_in[13];
  const float* cb2 = (const float*)d_in[14];
  const float* g2 = (const float*)d_in[15];
  const float* be2 = (const float*)d_in[16];
  const float* cw3 = (const float*)d_in[17];
  const float* cb3 = (const float*)d_in[18];
  const float* g3 = (const float*)d_in[19];
  const float* be3 = (const float*)d_in[20];
  const float* cw4 = (const float*)d_in[21];
  const float* cb4 = (const float*)d_in[22];
  const float* g4 = (const float*)d_in[23];
  const float* be4 = (const float*)d_in[24];
  const float* cw5 = (const float*)d_in[25];
  const float* cb5 = (const float*)d_in[26];

  char* p = (char*)d_ws;
  short* Y = (short*)p;    p += (size_t)512 * 627 * 192 * 2;
  short* INB = (short*)p;  p += (size_t)512 * 640 * 2;
  short* HB1 = (short*)p;  p += (size_t)512 * 1024 * 2;
  short* HB2 = (short*)p;  p += (size_t)512 * 1024 * 2;
  short* HB3 = (short*)p;  p += (size_t)512 * 1024 * 2;
  short* WB1 = (short*)p;  p += (size_t)1024 * 640 * 2;
  short* WB2 = (short*)p;  p += (size_t)1024 * 1024 * 2;
  short* WB3 = (short*)p;  p += (size_t)1024 * 1024 * 2;
  short* WB4 = (short*)p;  p += (size_t)1280 * 1024 * 2;
  short* CW2B = (short*)p; p += (size_t)192 * 96 * 2;
  short* CW3B = (short*)p; p += (size_t)192 * 192 * 2;
  short* CW4B = (short*)p; p += (size_t)192 * 192 * 2;
  short* CW5B = (short*)p; p += (size_t)320 * 192 * 2;
  float* fp = (float*)p;
  float* OUTB = fp;  fp += (size_t)512 * 1254;
  float* NLLB = fp;  fp += 321028;
  float* LLP = fp;   fp += 512;
  float* A1 = fp;    fp += 96;
  float* B1g = fp;   fp += 96;
  float* A2 = fp;    fp += 192;
  float* B2g = fp;   fp += 192;
  float* A3 = fp;    fp += 192;
  float* B3g = fp;   fp += 192;
  float* A4 = fp;    fp += 192;
  float* B4g = fp;   fp += 192;
  float* CB2P = fp;  fp += 192;
  float* CB3P = fp;  fp += 192;
  float* CB4P = fp;  fp += 192;
  float* CB5P = fp;  fp += 320;
  float* TST = fp;   fp += 2;
  float* SC = fp;    fp += 2;
  float* SPP = fp;   fp += (size_t)NSLOT * 180;
  float* QPP = fp;   fp += (size_t)NSLOT * 180;
  float* SRED = fp;  fp += NRED2 * 180;
  float* QRED = fp;  fp += NRED2 * 180;
  (void)NLLB;

  hipMemsetAsync(TST, 0, 4 * sizeof(float), stream);

  // fused prep (single launch)
  prep_all<<<dim3(PB_CB), 256, 0, stream>>>(
      inputs, INB, W_in, WB1, W_h1, WB2, W_h2, WB3, W_out, WB4,
      cw2, CW2B, cw3, CW3B, cw4, CW4B, cw5, CW5B,
      cb2, cb3, cb4, cb5, CB2P, CB3P, CB4P, CB5P);

  // masked MLP
  mlp_mfma<640><<<dim3(16, 16), 256, 0, stream>>>(INB, WB1, b_in, nullptr, HB1, 1024, 1);
  mlp_mfma<1024><<<dim3(16, 16), 256, 0, stream>>>(HB1, WB2, b_h1, nullptr, HB2, 1024, 1);
  mlp_mfma<1024><<<dim3(16, 16), 256, 0, stream>>>(HB2, WB3, b_h2, nullptr, HB3, 1024, 0);
  mlp_mfma<1024><<<dim3(20, 16), 256, 0, stream>>>(HB3, WB4, b_out, OUTB, nullptr, 1254, 0);

  // conv1+bn1 fold
  theta_stats<<<dim3(BATCH), 256, 0, stream>>>(OUTB, TST);
  finalize_conv1<<<1, 96, 0, stream>>>(TST, cw1, g1, be1, A1, B1g);

  // conv2 stats -> bn2 fold (10240 slots)
  conv2_stats<<<dim3(5, BATCH), 512, 0, stream>>>(OUTB, A1, B1g, CW2B, CB2P, SPP, QPP);
  bn_reduce1<<<dim3(NRED2), 192, 0, stream>>>(SPP, QPP, SRED, QRED);
  finalize_bn2<<<1, 192, 0, stream>>>(SRED, QRED, g2, be2, A2, B2g, NRED2);

  // fused conv2->conv3 (persistent, weights from L2) -> bn3 fold (5120 slots)
  fused_conv23<<<dim3(BATCH), 512, 0, stream>>>(OUTB, A1, B1g, CW2B, CB2P, A2, B2g, CW3B, CB3P, Y, SPP, QPP);
  bn_reduce1<<<dim3(NRED34), 192, 0, stream>>>(SPP, QPP, SRED, QRED);
  finalize_bn2<<<1, 192, 0, stream>>>(SRED, QRED, g3, be3, A3, B3g, NRED34);

  // conv4 (persistent + prefetch + reg stats, 1024 slots) -> bn4 fold
  conv4_ip<<<dim3(BATCH), 512, 0, stream>>>(Y, A3, B3g, CW4B, CB4P, SPP, QPP);
  bn_reduce1<<<dim3(NRED4), 192, 0, stream>>>(SPP, QPP, SRED, QRED);
  finalize_bn2<<<1, 192, 0, stream>>>(SRED, QRED, g4, be4, A4, B4g, NRED4);

  // conv5 + softmax + nll + ll (fused, weights from L2)
  conv5_nll_ll<<<dim3(BATCH), 512, 0, stream>>>(Y, A4, B4g, CW5B, CB5P, inputs, OUTB, LLP, SC);

  // final output
  ll_pass2<<<dim3(2), 256, 0, stream>>>(LLP, SC, (float*)d_out);
}

// Round 24
// 449.083 us; speedup vs baseline: 1.3664x; 1.3664x over previous
//
#include <hip/hip_runtime.h>
#include <hip/hip_bf16.h>
#include <math.h>

#define BATCH 512
#define NI 627
#define NH 1024
#define NOUTF 1254
#define LLEN 627
#define NBL (512 * 627)
#define EPSBN 1e-5f
#define NSLOT 10240
#define NRED2 40
#define NRED4 4

typedef __attribute__((ext_vector_type(8))) short bf16x8;
typedef __attribute__((ext_vector_type(4))) float f32x4;
typedef unsigned int uint32;
typedef unsigned short ushort16;

__device__ inline short f2b(float x) {
  __hip_bfloat16 h = __float2bfloat16(x);
  return *reinterpret_cast<short*>(&h);
}
__device__ inline float b2f(short s) {
  return __uint_as_float(((uint32)(ushort16)s) << 16);
}
__device__ inline f32x4 mfma16(bf16x8 a, bf16x8 b, f32x4 c) {
  return __builtin_amdgcn_mfma_f32_16x16x32_bf16(a, b, c, 0, 0, 0);
}
__device__ inline bf16x8 zero8() {
  bf16x8 z;
#pragma unroll
  for (int i = 0; i < 8; ++i) z[i] = 0;
  return z;
}
__device__ inline bf16x8 buildx1r(float4 alo, float4 ahi, float4 blo, float4 bhi, float th) {
  bf16x8 r;
  r[0] = f2b(fmaxf(fmaf(alo.x, th, blo.x), 0.f));
  r[1] = f2b(fmaxf(fmaf(alo.y, th, blo.y), 0.f));
  r[2] = f2b(fmaxf(fmaf(alo.z, th, blo.z), 0.f));
  r[3] = f2b(fmaxf(fmaf(alo.w, th, blo.w), 0.f));
  r[4] = f2b(fmaxf(fmaf(ahi.x, th, bhi.x), 0.f));
  r[5] = f2b(fmaxf(fmaf(ahi.y, th, bhi.y), 0.f));
  r[6] = f2b(fmaxf(fmaf(ahi.z, th, bhi.z), 0.f));
  r[7] = f2b(fmaxf(fmaf(ahi.w, th, bhi.w), 0.f));
  return r;
}
__device__ inline bf16x8 buildx1(const float* __restrict__ A1v, const float* __restrict__ B1v,
                                 int k0, float th) {
  float4 alo = *reinterpret_cast<const float4*>(&A1v[k0]);
  float4 ahi = *reinterpret_cast<const float4*>(&A1v[k0 + 4]);
  float4 blo = *reinterpret_cast<const float4*>(&B1v[k0]);
  float4 bhi = *reinterpret_cast<const float4*>(&B1v[k0 + 4]);
  return buildx1r(alo, ahi, blo, bhi, th);
}

// ================= fused prep =================
__device__ inline void prep_mlpw_elem(const float* W, short* Wb, int i,
                                      int Nreal, int Kreal, int Kpad, int mode) {
  int n = i / Kpad, k = i - n * Kpad;
  float w = 0.f;
  if (n < Nreal && k < Kreal) {
    int od = n >= 627 ? n - 627 : n;
    int kd = k >= 627 ? k - 627 : k;
    bool keep = (mode == 0) ? (od >= k) : (mode == 1) ? (od >= kd) : (od > kd);
    if (keep) w = W[n * Kreal + k];
  }
  Wb[i] = f2b(w);
}
__device__ inline void prep_convw_elem(const float* W, short* Wb, int i,
                                       int Oreal, int Kreal, int Kpad) {
  int o = i / Kpad, k = i - o * Kpad;
  Wb[i] = (o < Oreal && k < Kreal) ? f2b(W[o * Kreal + k]) : (short)0;
}

#define PB_INB   1280
#define PB_WB1   (PB_INB + 2560)
#define PB_WB2   (PB_WB1 + 4096)
#define PB_WB3   (PB_WB2 + 4096)
#define PB_WB4   (PB_WB3 + 5120)
#define PB_CW2   (PB_WB4 + 72)
#define PB_CW3   (PB_CW2 + 144)
#define PB_CW4   (PB_CW3 + 144)
#define PB_CW5   (PB_CW4 + 240)
#define PB_CB    (PB_CW5 + 2)

__global__ __launch_bounds__(256) void prep_all(
    const float* __restrict__ inputs, short* __restrict__ INB,
    const float* __restrict__ W_in, short* __restrict__ WB1,
    const float* __restrict__ W_h1, short* __restrict__ WB2,
    const float* __restrict__ W_h2, short* __restrict__ WB3,
    const float* __restrict__ W_out, short* __restrict__ WB4,
    const float* __restrict__ cw2, short* __restrict__ CW2B,
    const float* __restrict__ cw3, short* __restrict__ CW3B,
    const float* __restrict__ cw4, short* __restrict__ CW4B,
    const float* __restrict__ cw5, short* __restrict__ CW5B,
    const float* __restrict__ cb2, const float* __restrict__ cb3,
    const float* __restrict__ cb4, const float* __restrict__ cb5,
    float* __restrict__ cb2p, float* __restrict__ cb3p,
    float* __restrict__ cb4p, float* __restrict__ cb5p)
{
  const int bid = blockIdx.x;
  if (bid < PB_INB) {
    int i = bid * 256 + threadIdx.x;
    if (i < 512 * 640) {
      int m = i / 640, k = i - m * 640;
      INB[i] = (k < NI) ? f2b(inputs[m * NI + k]) : (short)0;
    }
  } else if (bid < PB_WB1) {
    int i = (bid - PB_INB) * 256 + threadIdx.x;
    if (i < 1024 * 640) prep_mlpw_elem(W_in, WB1, i, 1024, 627, 640, 0);
  } else if (bid < PB_WB2) {
    int i = (bid - PB_WB1) * 256 + threadIdx.x;
    prep_mlpw_elem(W_h1, WB2, i, 1024, 1024, 1024, 1);
  } else if (bid < PB_WB3) {
    int i = (bid - PB_WB2) * 256 + threadIdx.x;
    prep_mlpw_elem(W_h2, WB3, i, 1024, 1024, 1024, 1);
  } else if (bid < PB_WB4) {
    int i = (bid - PB_WB3) * 256 + threadIdx.x;
    if (i < 1280 * 1024) prep_mlpw_elem(W_out, WB4, i, 1254, 1024, 1024, 2);
  } else if (bid < PB_CW2) {
    int i = (bid - PB_WB4) * 256 + threadIdx.x;
    if (i < 192 * 96) prep_convw_elem(cw2, CW2B, i, 180, 90, 96);
  } else if (bid < PB_CW3) {
    int i = (bid - PB_CW2) * 256 + threadIdx.x;
    if (i < 192 * 192) prep_convw_elem(cw3, CW3B, i, 180, 180, 192);
  } else if (bid < PB_CW4) {
    int i = (bid - PB_CW3) * 256 + threadIdx.x;
    if (i < 192 * 192) prep_convw_elem(cw4, CW4B, i, 180, 180, 192);
  } else if (bid < PB_CW5) {
    int i = (bid - PB_CW4) * 256 + threadIdx.x;
    if (i < 320 * 192) prep_convw_elem(cw5, CW5B, i, 300, 180, 192);
  } else {
    int c = (bid - PB_CW5) * 256 + threadIdx.x;
    if (c < 192) {
      cb2p[c] = (c < 180) ? cb2[c] : 0.f;
      cb3p[c] = (c < 180) ? cb3[c] : 0.f;
      cb4p[c] = (c < 180) ? cb4[c] : 0.f;
    }
    if (c < 320) cb5p[c] = (c < 300) ? cb5[c] : 0.f;
  }
}

// ====== MLP MFMA GEMM ======
template<int KPAD>
__global__ __launch_bounds__(256) void mlp_mfma(
    const short* __restrict__ A, const short* __restrict__ Wb, const float* __restrict__ bias,
    float* __restrict__ Cf, short* __restrict__ Cb, int Nreal, int relu)
{
  __shared__ float red[2][2][2][4][64];
  const int tid = threadIdx.x;
  const int l = tid & 63, wv = tid >> 6;
  const int wn = wv >> 1, kh = wv & 1;
  const int m0 = blockIdx.y * 32;
  const int n0 = blockIdx.x * 64 + wn * 32;
  const int lr = l & 15, lk = (l >> 4) * 8, lm4 = (l >> 4) * 4;
  f32x4 acc[2][2] = {};
  constexpr int khalf = KPAD >> 1;
  constexpr int nk = khalf >> 5;
#pragma unroll
  for (int ks = 0; ks < nk; ++ks) {
    int k0 = kh * khalf + ks * 32 + lk;
    bf16x8 a0 = *reinterpret_cast<const bf16x8*>(&A[(size_t)(m0 + lr) * KPAD + k0]);
    bf16x8 a1 = *reinterpret_cast<const bf16x8*>(&A[(size_t)(m0 + 16 + lr) * KPAD + k0]);
    bf16x8 b0 = *reinterpret_cast<const bf16x8*>(&Wb[(size_t)(n0 + lr) * KPAD + k0]);
    bf16x8 b1 = *reinterpret_cast<const bf16x8*>(&Wb[(size_t)(n0 + 16 + lr) * KPAD + k0]);
    acc[0][0] = mfma16(a0, b0, acc[0][0]);
    acc[0][1] = mfma16(a0, b1, acc[0][1]);
    acc[1][0] = mfma16(a1, b0, acc[1][0]);
    acc[1][1] = mfma16(a1, b1, acc[1][1]);
  }
  if (kh == 1) {
#pragma unroll
    for (int mi = 0; mi < 2; ++mi)
#pragma unroll
      for (int nj = 0; nj < 2; ++nj)
#pragma unroll
        for (int r = 0; r < 4; ++r) red[wn][mi][nj][r][l] = acc[mi][nj][r];
  }
  __syncthreads();
  if (kh == 0) {
#pragma unroll
    for (int mi = 0; mi < 2; ++mi)
#pragma unroll
      for (int nj = 0; nj < 2; ++nj) {
        int n = n0 + nj * 16 + lr;
        if (n >= Nreal) continue;
        float bi = bias[n];
#pragma unroll
        for (int r = 0; r < 4; ++r) {
          int m = m0 + mi * 16 + lm4 + r;
          float v = acc[mi][nj][r] + red[wn][mi][nj][r][l] + bi;
          if (relu) v = fmaxf(v, 0.f);
          if (Cb) Cb[(size_t)m * Nreal + n] = f2b(v);
          else Cf[(size_t)m * Nreal + n] = v;
        }
      }
  }
}

// ================= theta stats =================
__global__ __launch_bounds__(256) void theta_stats(const float* __restrict__ outb, float* __restrict__ tstat)
{
  int b = blockIdx.x;
  const float* th = outb + (size_t)b * NOUTF + NI;
  float s = 0.f, q = 0.f;
  for (int l = threadIdx.x; l < LLEN; l += 256) { float t = th[l]; s += t; q += t * t; }
  for (int off = 1; off < 64; off <<= 1) { s += __shfl_xor(s, off); q += __shfl_xor(q, off); }
  __shared__ float tmp[8];
  int w = threadIdx.x >> 6;
  if ((threadIdx.x & 63) == 0) { tmp[w] = s; tmp[4 + w] = q; }
  __syncthreads();
  if (threadIdx.x == 0) {
    atomicAdd(&tstat[0], tmp[0] + tmp[1] + tmp[2] + tmp[3]);
    atomicAdd(&tstat[1], tmp[4] + tmp[5] + tmp[6] + tmp[7]);
  }
}

__global__ void finalize_conv1(const float* __restrict__ tstat, const float* __restrict__ cw1,
                               const float* __restrict__ g1, const float* __restrict__ be1,
                               float* __restrict__ a1, float* __restrict__ b1)
{
  int c = threadIdx.x;  // 96
  if (c >= 96) return;
  if (c < 90) {
    float mt = tstat[0] / (float)NBL;
    float vt = tstat[1] / (float)NBL - mt * mt;
    float w = cw1[c];
    float rs = rsqrtf(w * w * vt + EPSBN);
    float a = w * g1[c] * rs;
    a1[c] = a;
    b1[c] = be1[c] - a * mt;
  } else { a1[c] = 0.f; b1[c] = 0.f; }
}

// ============ BN stats reduction ============
__global__ __launch_bounds__(192) void bn_reduce1(const float* __restrict__ Sp, const float* __restrict__ Qp,
                                                  float* __restrict__ Sred, float* __restrict__ Qred)
{
  int c = threadIdx.x;
  if (c >= 180) return;
  int base = blockIdx.x * 256;
  float s = 0.f, q = 0.f;
  for (int r = 0; r < 256; ++r) {
    s += Sp[(size_t)(base + r) * 180 + c];
    q += Qp[(size_t)(base + r) * 180 + c];
  }
  Sred[blockIdx.x * 180 + c] = s;
  Qred[blockIdx.x * 180 + c] = q;
}

__global__ void finalize_bn2(const float* __restrict__ Sred, const float* __restrict__ Qred,
                             const float* __restrict__ g, const float* __restrict__ be,
                             float* __restrict__ aP, float* __restrict__ bP, int nred)
{
  int c = threadIdx.x;  // 192
  if (c >= 192) return;
  if (c < 180) {
    float s = 0.f, q = 0.f;
    for (int p = 0; p < nred; ++p) { s += Sred[p * 180 + c]; q += Qred[p * 180 + c]; }
    float m = s / (float)NBL;
    float v = q / (float)NBL - m * m;
    float a = g[c] * rsqrtf(v + EPSBN);
    aP[c] = a;
    bP[c] = be[c] - m * a;
  } else { aP[c] = 0.f; bP[c] = 0.f; }
}

// ================= conv2 stats-only =================
__global__ __launch_bounds__(512) void conv2_stats(
    const float* __restrict__ OUTB, const float* __restrict__ A1v, const float* __restrict__ B1v,
    const short* __restrict__ cw2b, const float* __restrict__ cb2p,
    float* __restrict__ Sp, float* __restrict__ Qp)
{
  const int tid = threadIdx.x;
  const int b = blockIdx.y, j0 = blockIdx.x * 128;
  const int l = tid & 63, wv = tid >> 6, wm = wv >> 2, wn = wv & 3;
  const int lr = l & 15, lk = (l >> 4) * 8, lm4 = (l >> 4) * 4;
  const int jj0 = j0 + wn * 32 + lr, jj1 = jj0 + 16;
  const float th0 = (jj0 < LLEN) ? OUTB[(size_t)b * NOUTF + NI + jj0] : 0.f;
  const float th1 = (jj1 < LLEN) ? OUTB[(size_t)b * NOUTF + NI + jj1] : 0.f;
  f32x4 acc[6][2] = {};
#pragma unroll
  for (int ks = 0; ks < 3; ++ks) {
    int k0 = ks * 32 + lk;
    bf16x8 b0 = buildx1(A1v, B1v, k0, th0);
    bf16x8 b1 = buildx1(A1v, B1v, k0, th1);
#pragma unroll
    for (int mi = 0; mi < 6; ++mi) {
      bf16x8 av = *reinterpret_cast<const bf16x8*>(&cw2b[(wm * 96 + mi * 16 + lr) * 96 + k0]);
      acc[mi][0] = mfma16(av, b0, acc[mi][0]);
      acc[mi][1] = mfma16(av, b1, acc[mi][1]);
    }
  }
  const size_t slot = (size_t)(blockIdx.y * gridDim.x + blockIdx.x) * 4 + wn;
#pragma unroll
  for (int mi = 0; mi < 6; ++mi) {
    int m0c = wm * 96 + mi * 16 + lm4;
    float s4[4] = {0.f, 0.f, 0.f, 0.f}, q4[4] = {0.f, 0.f, 0.f, 0.f};
#pragma unroll
    for (int nj = 0; nj < 2; ++nj) {
      int jj = j0 + wn * 32 + nj * 16 + lr;
      if (jj < LLEN) {
#pragma unroll
        for (int r = 0; r < 4; ++r) {
          float v = acc[mi][nj][r] + cb2p[m0c + r];
          s4[r] += v; q4[r] += v * v;
        }
      }
    }
#pragma unroll
    for (int off = 1; off < 16; off <<= 1)
#pragma unroll
      for (int r = 0; r < 4; ++r) { s4[r] += __shfl_xor(s4[r], off); q4[r] += __shfl_xor(q4[r], off); }
    if (lr == 0) {
#pragma unroll
      for (int r = 0; r < 4; ++r) {
        int o = m0c + r;
        if (o < 180) {
          Sp[slot * 180 + o] = s4[r];
          Qp[slot * 180 + o] = q4[r];
        }
      }
    }
  }
}

// ==== fused conv2->bn2->relu->conv3: PERSISTENT (LDS weights) + reg stats ====
__global__ __launch_bounds__(512) void fused_conv23(
    const float* __restrict__ OUTB, const float* __restrict__ A1v, const float* __restrict__ B1v,
    const short* __restrict__ cw2b, const float* __restrict__ cb2p,
    const float* __restrict__ a2, const float* __restrict__ b2,
    const short* __restrict__ cw3b, const float* __restrict__ cb3p,
    short* __restrict__ Y, float* __restrict__ Sp, float* __restrict__ Qp)
{
  __shared__ short wl2[192][98];
  __shared__ short wl3[192][196];
  __shared__ short xT2[128][196];
  const int tid = threadIdx.x;
  const int b = blockIdx.x;
  for (int t = tid; t < 192 * 12; t += 512) {
    int row = t / 12, c8 = (t - row * 12) * 8;
    *reinterpret_cast<bf16x8*>(&wl2[row][c8]) = *reinterpret_cast<const bf16x8*>(&cw2b[row * 96 + c8]);
  }
  for (int t = tid; t < 192 * 24; t += 512) {
    int row = t / 24, c8 = (t - row * 24) * 8;
    *reinterpret_cast<bf16x8*>(&wl3[row][c8]) = *reinterpret_cast<const bf16x8*>(&cw3b[row * 192 + c8]);
  }
  const int l = tid & 63, wv = tid >> 6, wm = wv >> 1, wn = wv & 1;
  const int lr = l & 15, lk = (l >> 4) * 8, lm4 = (l >> 4) * 4;
  float a2r[3][4], f2r[3][4], cb3r[3][4];
#pragma unroll
  for (int mi = 0; mi < 3; ++mi)
#pragma unroll
    for (int r = 0; r < 4; ++r) {
      int c = wm * 48 + mi * 16 + lm4 + r;
      float a = a2[c];
      a2r[mi][r] = a;
      f2r[mi][r] = fmaf(a, cb2p[c], b2[c]);
      cb3r[mi][r] = cb3p[c];
    }
  float sacc[3][4] = {}, qacc[3][4] = {};
  __syncthreads();
  for (int tile = 0; tile < 5; ++tile) {
    const int j0 = tile * 128;
    float th[4];
#pragma unroll
    for (int nj = 0; nj < 4; ++nj) {
      int jj = j0 + wn * 64 + nj * 16 + lr;
      th[nj] = (jj < LLEN) ? OUTB[(size_t)b * NOUTF + NI + jj] : 0.f;
    }
    f32x4 acc[3][4] = {};
#pragma unroll
    for (int ks = 0; ks < 3; ++ks) {
      int k0 = ks * 32 + lk;
      float4 alo = *reinterpret_cast<const float4*>(&A1v[k0]);
      float4 ahi = *reinterpret_cast<const float4*>(&A1v[k0 + 4]);
      float4 blo = *reinterpret_cast<const float4*>(&B1v[k0]);
      float4 bhi = *reinterpret_cast<const float4*>(&B1v[k0 + 4]);
      bf16x8 bb[4];
#pragma unroll
      for (int nj = 0; nj < 4; ++nj) bb[nj] = buildx1r(alo, ahi, blo, bhi, th[nj]);
      bf16x8 av[3];
#pragma unroll
      for (int mi = 0; mi < 3; ++mi)
        av[mi] = *reinterpret_cast<const bf16x8*>(&wl2[wm * 48 + mi * 16 + lr][k0]);
#pragma unroll
      for (int mi = 0; mi < 3; ++mi)
#pragma unroll
        for (int nj = 0; nj < 4; ++nj)
          acc[mi][nj] = mfma16(av[mi], bb[nj], acc[mi][nj]);
    }
    __syncthreads();
#pragma unroll
    for (int mi = 0; mi < 3; ++mi) {
      int m0c = wm * 48 + mi * 16 + lm4;
#pragma unroll
      for (int nj = 0; nj < 4; ++nj) {
        int col = wn * 64 + nj * 16 + lr;
        float x0 = fmaxf(fmaf(a2r[mi][0], acc[mi][nj][0], f2r[mi][0]), 0.f);
        float x1 = fmaxf(fmaf(a2r[mi][1], acc[mi][nj][1], f2r[mi][1]), 0.f);
        float x2 = fmaxf(fmaf(a2r[mi][2], acc[mi][nj][2], f2r[mi][2]), 0.f);
        float x3 = fmaxf(fmaf(a2r[mi][3], acc[mi][nj][3], f2r[mi][3]), 0.f);
        uint2 w2;
        w2.x = (uint32)(ushort16)f2b(x0) | ((uint32)(ushort16)f2b(x1) << 16);
        w2.y = (uint32)(ushort16)f2b(x2) | ((uint32)(ushort16)f2b(x3) << 16);
        *reinterpret_cast<uint2*>(&xT2[col][m0c]) = w2;
      }
    }
    __syncthreads();
    f32x4 acc2[3][4] = {};
#pragma unroll
    for (int ks = 0; ks < 6; ++ks) {
      int k0 = ks * 32 + lk;
      bf16x8 bb[4];
#pragma unroll
      for (int nj = 0; nj < 4; ++nj)
        bb[nj] = *reinterpret_cast<const bf16x8*>(&xT2[wn * 64 + nj * 16 + lr][k0]);
      bf16x8 av[3];
#pragma unroll
      for (int mi = 0; mi < 3; ++mi)
        av[mi] = *reinterpret_cast<const bf16x8*>(&wl3[wm * 48 + mi * 16 + lr][k0]);
#pragma unroll
      for (int mi = 0; mi < 3; ++mi)
#pragma unroll
        for (int nj = 0; nj < 4; ++nj)
          acc2[mi][nj] = mfma16(av[mi], bb[nj], acc2[mi][nj]);
    }
    __syncthreads();
#pragma unroll
    for (int mi = 0; mi < 3; ++mi) {
      int m0c = wm * 48 + mi * 16 + lm4;
#pragma unroll
      for (int nj = 0; nj < 4; ++nj) {
        int col = wn * 64 + nj * 16 + lr;
        int jj = j0 + col;
        float v0 = acc2[mi][nj][0] + cb3r[mi][0];
        float v1 = acc2[mi][nj][1] + cb3r[mi][1];
        float v2 = acc2[mi][nj][2] + cb3r[mi][2];
        float v3 = acc2[mi][nj][3] + cb3r[mi][3];
        if (jj < LLEN) {
          sacc[mi][0] += v0; qacc[mi][0] += v0 * v0;
          sacc[mi][1] += v1; qacc[mi][1] += v1 * v1;
          sacc[mi][2] += v2; qacc[mi][2] += v2 * v2;
          sacc[mi][3] += v3; qacc[mi][3] += v3 * v3;
        }
        uint2 w2;
        w2.x = (uint32)(ushort16)f2b(v0) | ((uint32)(ushort16)f2b(v1) << 16);
        w2.y = (uint32)(ushort16)f2b(v2) | ((uint32)(ushort16)f2b(v3) << 16);
        *reinterpret_cast<uint2*>(&xT2[col][m0c]) = w2;
      }
    }
    __syncthreads();
    for (int f = tid; f < 128 * 24; f += 512) {
      int row = f / 24, c0 = (f - row * 24) * 8;
      int jj = j0 + row;
      if (jj < LLEN) {
        bf16x8 v = *reinterpret_cast<const bf16x8*>(&xT2[row][c0]);
        *reinterpret_cast<bf16x8*>(&Y[((size_t)b * 627 + jj) * 192 + c0]) = v;
      }
    }
    __syncthreads();
  }
  // final stats write (once per block)
  const size_t slot = (size_t)b * 2 + wn;
#pragma unroll
  for (int mi = 0; mi < 3; ++mi) {
#pragma unroll
    for (int off = 1; off < 16; off <<= 1)
#pragma unroll
      for (int r = 0; r < 4; ++r) {
        sacc[mi][r] += __shfl_xor(sacc[mi][r], off);
        qacc[mi][r] += __shfl_xor(qacc[mi][r], off);
      }
    if (lr == 0) {
      int m0c = wm * 48 + mi * 16 + lm4;
#pragma unroll
      for (int r = 0; r < 4; ++r) {
        int o = m0c + r;
        if (o < 180) {
          Sp[slot * 180 + o] = sacc[mi][r];
          Qp[slot * 180 + o] = qacc[mi][r];
        }
      }
    }
  }
}

// ====== conv4 in place on Y: PERSISTENT + register Y-prefetch (T14) + reg stats ======
__global__ __launch_bounds__(512) void conv4_ip(
    short* __restrict__ Y, const float* __restrict__ a3, const float* __restrict__ b3,
    const short* __restrict__ cw4b, const float* __restrict__ cb4p,
    float* __restrict__ Sp, float* __restrict__ Qp)
{
  __shared__ short wl4[192][196];  // 75.3 KB
  __shared__ short xT[128][196];   // 50.2 KB
  __shared__ float ab[384];        // 1.5 KB
  const int tid = threadIdx.x;
  const int b = blockIdx.x;
  for (int t = tid; t < 192 * 24; t += 512) {
    int row = t / 24, c8 = (t - row * 24) * 8;
    *reinterpret_cast<bf16x8*>(&wl4[row][c8]) = *reinterpret_cast<const bf16x8*>(&cw4b[row * 192 + c8]);
  }
  for (int t = tid; t < 384; t += 512) ab[t] = (t < 192) ? a3[t] : b3[t - 192];
  const int l = tid & 63, wv = tid >> 6, wm = wv >> 1, wn = wv & 1;
  const int lr = l & 15, lk = (l >> 4) * 8, lm4 = (l >> 4) * 4;
  float cb4r[3][4];
#pragma unroll
  for (int mi = 0; mi < 3; ++mi)
#pragma unroll
    for (int r = 0; r < 4; ++r)
      cb4r[mi][r] = cb4p[wm * 48 + mi * 16 + lm4 + r];
  // prefetch tile 0 raw Y (6 chunks/thread)
  bf16x8 raw[6];
#pragma unroll
  for (int s = 0; s < 6; ++s) {
    int t = tid + s * 512;
    int col = t / 24, c8 = (t - col * 24) * 8;
    raw[s] = (col < LLEN) ? *reinterpret_cast<const bf16x8*>(&Y[((size_t)b * 627 + col) * 192 + c8]) : zero8();
  }
  float sacc[3][4] = {}, qacc[3][4] = {};
  __syncthreads();  // wl4/ab visible
  for (int tile = 0; tile < 5; ++tile) {
    const int j0 = tile * 128;
    // convert prefetched raw -> xT (x3 = relu(a3*y3+b3))
#pragma unroll
    for (int s = 0; s < 6; ++s) {
      int t = tid + s * 512;
      int col = t / 24, c8 = (t - col * 24) * 8;
      int jj = j0 + col;
      bf16x8 pk;
      if (jj < LLEN) {
#pragma unroll
        for (int i = 0; i < 8; ++i)
          pk[i] = f2b(fmaxf(fmaf(ab[c8 + i], b2f(raw[s][i]), ab[192 + c8 + i]), 0.f));
      } else {
        pk = zero8();
      }
      *reinterpret_cast<bf16x8*>(&xT[col][c8]) = pk;
    }
    __syncthreads();  // xT ready
    f32x4 acc[3][4] = {};
#pragma unroll
    for (int ks = 0; ks < 6; ++ks) {
      int k0 = ks * 32 + lk;
      bf16x8 bb[4];
#pragma unroll
      for (int nj = 0; nj < 4; ++nj)
        bb[nj] = *reinterpret_cast<const bf16x8*>(&xT[wn * 64 + nj * 16 + lr][k0]);
      bf16x8 av[3];
#pragma unroll
      for (int mi = 0; mi < 3; ++mi)
        av[mi] = *reinterpret_cast<const bf16x8*>(&wl4[wm * 48 + mi * 16 + lr][k0]);
#pragma unroll
      for (int mi = 0; mi < 3; ++mi)
#pragma unroll
        for (int nj = 0; nj < 4; ++nj)
          acc[mi][nj] = mfma16(av[mi], bb[nj], acc[mi][nj]);
    }
    // issue next tile's Y loads (latency hidden under epilogue + copy-out)
    if (tile < 4) {
#pragma unroll
      for (int s = 0; s < 6; ++s) {
        int t = tid + s * 512;
        int col = t / 24, c8 = (t - col * 24) * 8;
        int jj = j0 + 128 + col;
        raw[s] = (jj < LLEN) ? *reinterpret_cast<const bf16x8*>(&Y[((size_t)b * 627 + jj) * 192 + c8]) : zero8();
      }
    }
    __syncthreads();  // MFMA xT reads done; reuse xT as y4 staging
#pragma unroll
    for (int mi = 0; mi < 3; ++mi) {
      int m0c = wm * 48 + mi * 16 + lm4;
#pragma unroll
      for (int nj = 0; nj < 4; ++nj) {
        int col = wn * 64 + nj * 16 + lr;
        int jj = j0 + col;
        float v0 = acc[mi][nj][0] + cb4r[mi][0];
        float v1 = acc[mi][nj][1] + cb4r[mi][1];
        float v2 = acc[mi][nj][2] + cb4r[mi][2];
        float v3 = acc[mi][nj][3] + cb4r[mi][3];
        if (jj < LLEN) {
          sacc[mi][0] += v0; qacc[mi][0] += v0 * v0;
          sacc[mi][1] += v1; qacc[mi][1] += v1 * v1;
          sacc[mi][2] += v2; qacc[mi][2] += v2 * v2;
          sacc[mi][3] += v3; qacc[mi][3] += v3 * v3;
        }
        uint2 w2;
        w2.x = (uint32)(ushort16)f2b(v0) | ((uint32)(ushort16)f2b(v1) << 16);
        w2.y = (uint32)(ushort16)f2b(v2) | ((uint32)(ushort16)f2b(v3) << 16);
        *reinterpret_cast<uint2*>(&xT[col][m0c]) = w2;
      }
    }
    __syncthreads();  // y4 staged
    for (int f = tid; f < 128 * 24; f += 512) {
      int row = f / 24, c0 = (f - row * 24) * 8;
      int jj = j0 + row;
      if (jj < LLEN) {
        bf16x8 v = *reinterpret_cast<const bf16x8*>(&xT[row][c0]);
        *reinterpret_cast<bf16x8*>(&Y[((size_t)b * 627 + jj) * 192 + c0]) = v;
      }
    }
    __syncthreads();  // copy-out reads done before next convert overwrites xT
  }
  // final stats write (once per block)
  const size_t slot = (size_t)b * 2 + wn;
#pragma unroll
  for (int mi = 0; mi < 3; ++mi) {
#pragma unroll
    for (int off = 1; off < 16; off <<= 1)
#pragma unroll
      for (int r = 0; r < 4; ++r) {
        sacc[mi][r] += __shfl_xor(sacc[mi][r], off);
        qacc[mi][r] += __shfl_xor(qacc[mi][r], off);
      }
    if (lr == 0) {
      int m0c = wm * 48 + mi * 16 + lm4;
#pragma unroll
      for (int r = 0; r < 4; ++r) {
        int o = m0c + r;
        if (o < 180) {
          Sp[slot * 180 + o] = sacc[mi][r];
          Qp[slot * 180 + o] = qacc[mi][r];
        }
      }
    }
  }
}

// ==== conv5 + softmax + NLL + ll reduction (persistent LDS weights, 1-barrier softmax) ====
__global__ __launch_bounds__(512) void conv5_nll_ll(
    const short* __restrict__ Y, const float* __restrict__ a4, const float* __restrict__ b4,
    const short* __restrict__ cw5b, const float* __restrict__ cb5p,
    const float* __restrict__ inputs, const float* __restrict__ outb,
    float* __restrict__ llp, float* __restrict__ sc)
{
  __shared__ short wlds[320][200];
  __shared__ short xT[64][200];
  __shared__ int tga[640];
  __shared__ float wmax[4][64];
  __shared__ float wsum[4][64];
  __shared__ float ptgt[64];
  __shared__ float nlls[640];
  const int tid = threadIdx.x;
  const int b = blockIdx.x;
  for (int t = tid; t < 320 * 24; t += 512) {
    int row = t / 24, c8 = (t - row * 24) * 8;
    *reinterpret_cast<bf16x8*>(&wlds[row][c8]) =
        *reinterpret_cast<const bf16x8*>(&cw5b[row * 192 + c8]);
  }
  for (int t = tid; t < 640; t += 512)
    tga[t] = (t < LLEN) ? (int)inputs[(size_t)b * NI + t] : 0;
  const int l = tid & 63, wv = tid >> 6;
  const int wm = wv >> 1, wn = wv & 1;
  const int lr = l & 15, lk = (l >> 4) * 8, lm4 = (l >> 4) * 4;
  const int mf0 = wm * 5;
  float aa[3][8], bb4[3][8];
#pragma unroll
  for (int s = 0; s < 3; ++s) {
    int t = tid + s * 512;
    int c8 = (t % 24) * 8;
#pragma unroll
    for (int i = 0; i < 8; ++i) { aa[s][i] = a4[c8 + i]; bb4[s][i] = b4[c8 + i]; }
  }
  float cbr[5][4];
#pragma unroll
  for (int mi = 0; mi < 5; ++mi)
#pragma unroll
    for (int r = 0; r < 4; ++r)
      cbr[mi][r] = cb5p[(mf0 + mi) * 16 + lm4 + r];
  bf16x8 raw[3];
#pragma unroll
  for (int s = 0; s < 3; ++s) {
    int t = tid + s * 512;
    int col = t / 24, c8 = (t - col * 24) * 8;
    raw[s] = (col < LLEN) ? *reinterpret_cast<const bf16x8*>(&Y[((size_t)b * 627 + col) * 192 + c8]) : zero8();
  }
  __syncthreads();
  for (int tile = 0; tile < 10; ++tile) {
    const int l0 = tile * 64;
#pragma unroll
    for (int s = 0; s < 3; ++s) {
      int t = tid + s * 512;
      int col = t / 24, c8 = (t - col * 24) * 8;
      bf16x8 pk;
#pragma unroll
      for (int i = 0; i < 8; ++i)
        pk[i] = f2b(fmaxf(fmaf(aa[s][i], b2f(raw[s][i]), bb4[s][i]), 0.f));
      *reinterpret_cast<bf16x8*>(&xT[col][c8]) = pk;
    }
    __syncthreads();
    f32x4 acc[5][2] = {};
#pragma unroll
    for (int ks = 0; ks < 6; ++ks) {
      int k0 = ks * 32 + lk;
      bf16x8 bb0 = *reinterpret_cast<const bf16x8*>(&xT[wn * 32 + lr][k0]);
      bf16x8 bb1 = *reinterpret_cast<const bf16x8*>(&xT[wn * 32 + 16 + lr][k0]);
#pragma unroll
      for (int mi = 0; mi < 5; ++mi) {
        bf16x8 av = *reinterpret_cast<const bf16x8*>(&wlds[(mf0 + mi) * 16 + lr][k0]);
        acc[mi][0] = mfma16(av, bb0, acc[mi][0]);
        acc[mi][1] = mfma16(av, bb1, acc[mi][1]);
      }
    }
    if (tile < 9) {
#pragma unroll
      for (int s = 0; s < 3; ++s) {
        int t = tid + s * 512;
        int col = t / 24, c8 = (t - col * 24) * 8;
        int jj = l0 + 64 + col;
        raw[s] = (jj < LLEN) ? *reinterpret_cast<const bf16x8*>(&Y[((size_t)b * 627 + jj) * 192 + c8]) : zero8();
      }
    }
    float vmax0 = -1e30f, vmax1 = -1e30f;
    int t0 = tga[l0 + wn * 32 + lr], t1 = tga[l0 + wn * 32 + 16 + lr];
#pragma unroll
    for (int mi = 0; mi < 5; ++mi) {
#pragma unroll
      for (int r = 0; r < 4; ++r) {
        int m = (mf0 + mi) * 16 + lm4 + r;
        bool ok = (m < 300);
        float v0 = ok ? (acc[mi][0][r] + cbr[mi][r]) : -1e30f;
        float v1 = ok ? (acc[mi][1][r] + cbr[mi][r]) : -1e30f;
        acc[mi][0][r] = v0;
        acc[mi][1][r] = v1;
        vmax0 = fmaxf(vmax0, v0);
        vmax1 = fmaxf(vmax1, v1);
        if (m == t0) ptgt[wn * 32 + lr] = v0;
        if (m == t1) ptgt[wn * 32 + 16 + lr] = v1;
      }
    }
    vmax0 = fmaxf(vmax0, __shfl_xor(vmax0, 16)); vmax0 = fmaxf(vmax0, __shfl_xor(vmax0, 32));
    vmax1 = fmaxf(vmax1, __shfl_xor(vmax1, 16)); vmax1 = fmaxf(vmax1, __shfl_xor(vmax1, 32));
    float vs0 = 0.f, vs1 = 0.f;
#pragma unroll
    for (int mi = 0; mi < 5; ++mi)
#pragma unroll
      for (int r = 0; r < 4; ++r) {
        vs0 += __expf(acc[mi][0][r] - vmax0);
        vs1 += __expf(acc[mi][1][r] - vmax1);
      }
    vs0 += __shfl_xor(vs0, 16); vs0 += __shfl_xor(vs0, 32);
    vs1 += __shfl_xor(vs1, 16); vs1 += __shfl_xor(vs1, 32);
    if (l < 16) {
      wmax[wm][wn * 32 + lr] = vmax0; wmax[wm][wn * 32 + 16 + lr] = vmax1;
      wsum[wm][wn * 32 + lr] = vs0;   wsum[wm][wn * 32 + 16 + lr] = vs1;
    }
    __syncthreads();
    if (tid < 64) {
      int jj = l0 + tid;
      if (jj < LLEN) {
        float m0 = wmax[0][tid], m1 = wmax[1][tid], m2 = wmax[2][tid], m3 = wmax[3][tid];
        float gm = fmaxf(fmaxf(m0, m1), fmaxf(m2, m3));
        float gs = wsum[0][tid] * __expf(m0 - gm) + wsum[1][tid] * __expf(m1 - gm)
                 + wsum[2][tid] * __expf(m2 - gm) + wsum[3][tid] * __expf(m3 - gm);
        nlls[jj] = gm + logf(gs) - ptgt[tid];
      }
    }
  }
  __syncthreads();
  float s = 0.f;
  for (int lidx = 2 + tid; lidx < LLEN; lidx += 512) {
    float graw = outb[(size_t)b * NOUTF + lidx];
    float sg = 1.f / (1.f + expf(-graw));
    float term = (tga[lidx] > 0) ? (0.1f * logf(sg + 1e-10f) - nlls[lidx])
                                 : (0.1f * logf(1.f - sg + 1e-10f));
    s += term;
  }
  for (int off = 1; off < 64; off <<= 1) s += __shfl_xor(s, off);
  if (l == 0) wmax[0][wv] = s;
  __syncthreads();
  if (tid == 0) {
    float tot = 0.f;
#pragma unroll
    for (int w = 0; w < 8; ++w) tot += wmax[0][w];
    llp[b] = tot;
    atomicAdd(sc, nlls[0] + nlls[1]);
  }
}

__global__ void ll_pass2(const float* __restrict__ llp, const float* __restrict__ sc, float* __restrict__ outp)
{
  int i = blockIdx.x * blockDim.x + threadIdx.x;
  if (i < BATCH) outp[i] = llp[i] - sc[0] * (1.f / 1024.f);
}

extern "C" void kernel_launch(void* const* d_in, const int* in_sizes, int n_in,
                              void* d_out, int out_size, void* d_ws, size_t ws_size,
                              hipStream_t stream)
{
  const float* inputs = (const float*)d_in[0];
  const float* W_in = (const float*)d_in[1];
  const float* b_in = (const float*)d_in[2];
  const float* W_h1 = (const float*)d_in[3];
  const float* b_h1 = (const float*)d_in[4];
  const float* W_h2 = (const float*)d_in[5];
  const float* b_h2 = (const float*)d_in[6];
  const float* W_out = (const float*)d_in[7];
  const float* b_out = (const float*)d_in[8];
  const float* cw1 = (const float*)d_in[9];
  const float* g1 = (const float*)d_in[11];
  const float* be1 = (const float*)d_in[12];
  const float* cw2 = (const float*)d_in[13];
  const float* cb2 = (const float*)d_in[14];
  const float* g2 = (const float*)d_in[15];
  const float* be2 = (const float*)d_in[16];
  const float* cw3 = (const float*)d_in[17];
  const float* cb3 = (const float*)d_in[18];
  const float* g3 = (const float*)d_in[19];
  const float* be3 = (const float*)d_in[20];
  const float* cw4 = (const float*)d_in[21];
  const float* cb4 = (const float*)d_in[22];
  const float* g4 = (const float*)d_in[23];
  const float* be4 = (const float*)d_in[24];
  const float* cw5 = (const float*)d_in[25];
  const float* cb5 = (const float*)d_in[26];

  char* p = (char*)d_ws;
  short* Y = (short*)p;    p += (size_t)512 * 627 * 192 * 2;
  short* INB = (short*)p;  p += (size_t)512 * 640 * 2;
  short* HB1 = (short*)p;  p += (size_t)512 * 1024 * 2;
  short* HB2 = (short*)p;  p += (size_t)512 * 1024 * 2;
  short* HB3 = (short*)p;  p += (size_t)512 * 1024 * 2;
  short* WB1 = (short*)p;  p += (size_t)1024 * 640 * 2;
  short* WB2 = (short*)p;  p += (size_t)1024 * 1024 * 2;
  short* WB3 = (short*)p;  p += (size_t)1024 * 1024 * 2;
  short* WB4 = (short*)p;  p += (size_t)1280 * 1024 * 2;
  short* CW2B = (short*)p; p += (size_t)192 * 96 * 2;
  short* CW3B = (short*)p; p += (size_t)192 * 192 * 2;
  short* CW4B = (short*)p; p += (size_t)192 * 192 * 2;
  short* CW5B = (short*)p; p += (size_t)320 * 192 * 2;
  float* fp = (float*)p;
  float* OUTB = fp;  fp += (size_t)512 * 1254;
  float* NLLB = fp;  fp += 321028;
  float* LLP = fp;   fp += 512;
  float* A1 = fp;    fp += 96;
  float* B1g = fp;   fp += 96;
  float* A2 = fp;    fp += 192;
  float* B2g = fp;   fp += 192;
  float* A3 = fp;    fp += 192;
  float* B3g = fp;   fp += 192;
  float* A4 = fp;    fp += 192;
  float* B4g = fp;   fp += 192;
  float* CB2P = fp;  fp += 192;
  float* CB3P = fp;  fp += 192;
  float* CB4P = fp;  fp += 192;
  float* CB5P = fp;  fp += 320;
  float* TST = fp;   fp += 2;
  float* SC = fp;    fp += 2;
  float* SPP = fp;   fp += (size_t)NSLOT * 180;
  float* QPP = fp;   fp += (size_t)NSLOT * 180;
  float* SRED = fp;  fp += NRED2 * 180;
  float* QRED = fp;  fp += NRED2 * 180;
  (void)NLLB;

  hipMemsetAsync(TST, 0, 4 * sizeof(float), stream);

  // fused prep (single launch)
  prep_all<<<dim3(PB_CB), 256, 0, stream>>>(
      inputs, INB, W_in, WB1, W_h1, WB2, W_h2, WB3, W_out, WB4,
      cw2, CW2B, cw3, CW3B, cw4, CW4B, cw5, CW5B,
      cb2, cb3, cb4, cb5, CB2P, CB3P, CB4P, CB5P);

  // masked MLP
  mlp_mfma<640><<<dim3(16, 16), 256, 0, stream>>>(INB, WB1, b_in, nullptr, HB1, 1024, 1);
  mlp_mfma<1024><<<dim3(16, 16), 256, 0, stream>>>(HB1, WB2, b_h1, nullptr, HB2, 1024, 1);
  mlp_mfma<1024><<<dim3(16, 16), 256, 0, stream>>>(HB2, WB3, b_h2, nullptr, HB3, 1024, 0);
  mlp_mfma<1024><<<dim3(20, 16), 256, 0, stream>>>(HB3, WB4, b_out, OUTB, nullptr, 1254, 0);

  // conv1+bn1 fold
  theta_stats<<<dim3(BATCH), 256, 0, stream>>>(OUTB, TST);
  finalize_conv1<<<1, 96, 0, stream>>>(TST, cw1, g1, be1, A1, B1g);

  // conv2 stats -> bn2 fold (10240 slots)
  conv2_stats<<<dim3(5, BATCH), 512, 0, stream>>>(OUTB, A1, B1g, CW2B, CB2P, SPP, QPP);
  bn_reduce1<<<dim3(NRED2), 192, 0, stream>>>(SPP, QPP, SRED, QRED);
  finalize_bn2<<<1, 192, 0, stream>>>(SRED, QRED, g2, be2, A2, B2g, NRED2);

  // fused conv2->conv3 (persistent, LDS weights, reg stats -> 1024 slots) -> bn3 fold
  fused_conv23<<<dim3(BATCH), 512, 0, stream>>>(OUTB, A1, B1g, CW2B, CB2P, A2, B2g, CW3B, CB3P, Y, SPP, QPP);
  bn_reduce1<<<dim3(NRED4), 192, 0, stream>>>(SPP, QPP, SRED, QRED);
  finalize_bn2<<<1, 192, 0, stream>>>(SRED, QRED, g3, be3, A3, B3g, NRED4);

  // conv4 (persistent + prefetch + reg stats, 1024 slots) -> bn4 fold
  conv4_ip<<<dim3(BATCH), 512, 0, stream>>>(Y, A3, B3g, CW4B, CB4P, SPP, QPP);
  bn_reduce1<<<dim3(NRED4), 192, 0, stream>>>(SPP, QPP, SRED, QRED);
  finalize_bn2<<<1, 192, 0, stream>>>(SRED, QRED, g4, be4, A4, B4g, NRED4);

  // conv5 + softmax + nll + ll (fused, LDS weights)
  conv5_nll_ll<<<dim3(BATCH), 512, 0, stream>>>(Y, A4, B4g, CW5B, CB5P, inputs, OUTB, LLP, SC);

  // final output
  ll_pass2<<<dim3(2), 256, 0, stream>>>(LLP, SC, (float*)d_out);
}